// Round 4
// baseline (522.537 us; speedup 1.0000x reference)
//
#include <hip/hip_runtime.h>

// PerceptronSP: 8000 independent per-pixel MLPs sharing input x.
//   h1 = leaky(x @ W1[p] + b1[p])   [32x25]@[25x128]
//   h2 = leaky(h1 @ W2[p] + b2[p])  [32x128]@[128x128]
//   y[:,p] = h2 @ W3[p] + b3[p]
// Memory-bound: ~640 MB of weights streamed once -> ~100 us floor @ 6.6 TB/s.
//
// Mapping: ONE WAVE PER PIXEL. lane = bg*16+kg (bg=lane>>4, kg=lane&15).
//   lane owns rows 8*bg..8*bg+7  x  cols {4kg..4kg+3} u {64+4kg..64+4kg+3}.
// Round 3 -> 4: explicit register double-buffering of the W1/W2 streams so
// the next quad's 8 loads are in flight during the current quad's 256 FMAs
// (counted vmcnt, never a full drain) + bank-group XOR swizzle on h1s.

constexpr int DIM_IN = 25;
constexpr int H      = 128;
constexpr int P      = 8000;
constexpr int BS     = 32;
constexpr float NEG  = 0.01f;

__device__ __forceinline__ float leaky(float v) { return v >= 0.f ? v : NEG * v; }

__global__ __launch_bounds__(64, 2) void pixel_mlp_kernel(
    const float* __restrict__ x,    // [BS][DIM_IN]
    const float* __restrict__ W1,   // [P][DIM_IN][H]
    const float* __restrict__ b1,   // [P][H]
    const float* __restrict__ W2,   // [P][H][H]
    const float* __restrict__ b2,   // [P][H]
    const float* __restrict__ W3,   // [P][H]
    const float* __restrict__ b3,   // [P]
    float* __restrict__ y)          // [BS][P]
{
    const int p  = blockIdx.x;
    const int t  = threadIdx.x;     // 0..63, one wave
    const int kg = t & 15;          // col group: cols 4kg.. and 64+4kg..
    const int bg = t >> 4;          // row group: rows 8bg..8bg+7
    const int c0 = kg << 2;         // first col of low half
    const int r0 = bg << 3;         // first row
    const int sw = bg << 2;         // h1s bank swizzle (XOR on float index)

    __shared__ float sxT[DIM_IN][BS];   // x transposed: [d][b]
    __shared__ float h1s[BS][H];        // layer-1 activations, XOR-swizzled cols

    const float* W1p = W1 + (size_t)p * (DIM_IN * H);
    const float* W2p = W2 + (size_t)p * (H * H);

    // ---- hoisted small loads (issue early, consume late) ----
    const float4 b1l = *reinterpret_cast<const float4*>(b1 + (size_t)p * H + c0);
    const float4 b1h = *reinterpret_cast<const float4*>(b1 + (size_t)p * H + 64 + c0);
    const float4 b2l = *reinterpret_cast<const float4*>(b2 + (size_t)p * H + c0);
    const float4 b2h = *reinterpret_cast<const float4*>(b2 + (size_t)p * H + 64 + c0);
    const float4 w3l = *reinterpret_cast<const float4*>(W3 + (size_t)p * H + c0);
    const float4 w3h = *reinterpret_cast<const float4*>(W3 + (size_t)p * H + 64 + c0);

    // ---- W1 row loader / consumer (register double-buffer) ----
    float wa[8], wb[8];
    auto L1LOAD = [&](float (&w)[8], int d) {
        const float4 wl = *reinterpret_cast<const float4*>(W1p + d * H + c0);
        const float4 wh = *reinterpret_cast<const float4*>(W1p + d * H + 64 + c0);
        w[0]=wl.x; w[1]=wl.y; w[2]=wl.z; w[3]=wl.w;
        w[4]=wh.x; w[5]=wh.y; w[6]=wh.z; w[7]=wh.w;
    };

    L1LOAD(wa, 0);   // first W1 row in flight before x staging

    // stage x^T (800 elems, 64 threads)
    for (int i = t; i < DIM_IN * BS; i += 64) {
        const int d = i >> 5, b = i & 31;
        sxT[d][b] = x[b * DIM_IN + d];
    }
    __syncthreads();

    // ---------------- layer 1: h1 = leaky(x @ W1 + b1) ----------------
    float acc1[8][8];
    {
        const float bv[8] = {b1l.x, b1l.y, b1l.z, b1l.w, b1h.x, b1h.y, b1h.z, b1h.w};
        #pragma unroll
        for (int i = 0; i < 8; ++i)
            #pragma unroll
            for (int c = 0; c < 8; ++c)
                acc1[i][c] = bv[c];
    }
    auto L1FMA = [&](const float (&w)[8], int d) {
        const float4 a0 = *reinterpret_cast<const float4*>(&sxT[d][r0]);      // banks r0%32: 0/8/16/24 -> conflict-free
        const float4 a1 = *reinterpret_cast<const float4*>(&sxT[d][r0 + 4]);
        const float av[8] = {a0.x, a0.y, a0.z, a0.w, a1.x, a1.y, a1.z, a1.w};
        #pragma unroll
        for (int i = 0; i < 8; ++i)
            #pragma unroll
            for (int c = 0; c < 8; ++c)
                acc1[i][c] += av[i] * w[c];
    };

    #pragma unroll 1
    for (int d = 0; d < 24; d += 2) {      // d = 0,2,...,22
        L1LOAD(wb, d + 1);
        L1FMA(wa, d);
        L1LOAD(wa, d + 2);                  // up to d=24
        L1FMA(wb, d + 1);
    }
    L1FMA(wa, 24);

    // ---- W2 quad loader (register double-buffer) ----
    float wc[4][8], wn[4][8];
    auto LOADQ = [&](float (&w)[4][8], int h0) {
        #pragma unroll
        for (int r = 0; r < 4; ++r) {
            const float4 wl = *reinterpret_cast<const float4*>(W2p + (h0 + r) * H + c0);
            const float4 wh = *reinterpret_cast<const float4*>(W2p + (h0 + r) * H + 64 + c0);
            w[r][0]=wl.x; w[r][1]=wl.y; w[r][2]=wl.z; w[r][3]=wl.w;
            w[r][4]=wh.x; w[r][5]=wh.y; w[r][6]=wh.z; w[r][7]=wh.w;
        }
    };

    LOADQ(wc, 0);   // first W2 quad in flight before the h1 LDS writes

    // write h1 (leaky) with bank-group swizzle: float index ^= (bg<<2)
    #pragma unroll
    for (int i = 0; i < 8; ++i) {
        float4 ol, oh;
        ol.x = leaky(acc1[i][0]); ol.y = leaky(acc1[i][1]);
        ol.z = leaky(acc1[i][2]); ol.w = leaky(acc1[i][3]);
        oh.x = leaky(acc1[i][4]); oh.y = leaky(acc1[i][5]);
        oh.z = leaky(acc1[i][6]); oh.w = leaky(acc1[i][7]);
        *reinterpret_cast<float4*>(&h1s[r0 + i][c0 ^ sw])        = ol;
        *reinterpret_cast<float4*>(&h1s[r0 + i][(64 + c0) ^ sw]) = oh;
    }
    __syncthreads();

    // ---------------- layer 2: h2 = leaky(h1 @ W2 + b2) ----------------
    float acc2[8][8];
    {
        const float bv[8] = {b2l.x, b2l.y, b2l.z, b2l.w, b2h.x, b2h.y, b2h.z, b2h.w};
        #pragma unroll
        for (int i = 0; i < 8; ++i)
            #pragma unroll
            for (int c = 0; c < 8; ++c)
                acc2[i][c] = bv[c];
    }
    auto AVFMA = [&](const float (&w)[4][8], int h0) {
        #pragma unroll
        for (int i = 0; i < 8; ++i) {
            // swizzled read: 4 bg-groups hit 4 distinct bank slots -> conflict-free
            const float4 a4 = *reinterpret_cast<const float4*>(&h1s[r0 + i][h0 ^ sw]);
            const float av[4] = {a4.x, a4.y, a4.z, a4.w};
            #pragma unroll
            for (int r = 0; r < 4; ++r)
                #pragma unroll
                for (int c = 0; c < 8; ++c)
                    acc2[i][c] += av[r] * w[r][c];
        }
    };

    #pragma unroll 1
    for (int h0 = 0; h0 < H - 8; h0 += 8) {   // h0 = 0,8,...,112
        LOADQ(wn, h0 + 4);
        AVFMA(wc, h0);
        LOADQ(wc, h0 + 8);
        AVFMA(wn, h0 + 4);
    }
    LOADQ(wn, 124);
    AVFMA(wc, 120);
    AVFMA(wn, 124);

    // ---------------- layer 3: y = leaky(h2) @ W3 + b3 ----------------
    const float w3v[8] = {w3l.x, w3l.y, w3l.z, w3l.w, w3h.x, w3h.y, w3h.z, w3h.w};
    float part[8];
    #pragma unroll
    for (int i = 0; i < 8; ++i) {
        float s = 0.f;
        #pragma unroll
        for (int c = 0; c < 8; ++c)
            s += leaky(acc2[i][c]) * w3v[c];
        part[i] = s;
    }
    // reduce across the 16 kg lanes (xor masks 1,2,4,8 stay within the 16-group)
    #pragma unroll
    for (int m = 8; m >= 1; m >>= 1) {
        #pragma unroll
        for (int i = 0; i < 8; ++i)
            part[i] += __shfl_xor(part[i], m);
    }
    if (kg == 0) {
        const float bias = b3[p];
        #pragma unroll
        for (int i = 0; i < 8; ++i)
            y[(size_t)(r0 + i) * P + p] = part[i] + bias;
    }
}

extern "C" void kernel_launch(void* const* d_in, const int* in_sizes, int n_in,
                              void* d_out, int out_size, void* d_ws, size_t ws_size,
                              hipStream_t stream) {
    const float* x  = (const float*)d_in[0];
    const float* W1 = (const float*)d_in[1];
    const float* b1 = (const float*)d_in[2];
    const float* W2 = (const float*)d_in[3];
    const float* b2 = (const float*)d_in[4];
    const float* W3 = (const float*)d_in[5];
    const float* b3 = (const float*)d_in[6];
    float* y = (float*)d_out;

    pixel_mlp_kernel<<<dim3(P), dim3(64), 0, stream>>>(x, W1, b1, W2, b2, W3, b3, y);
}

// Round 5
// 519.065 us; speedup vs baseline: 1.0067x; 1.0067x over previous
//
#include <hip/hip_runtime.h>

// PerceptronSP: 8000 independent per-pixel MLPs sharing input x.
//   h1 = leaky(x @ W1[p] + b1[p])   [32x25]@[25x128]
//   h2 = leaky(h1 @ W2[p] + b2[p])  [32x128]@[128x128]
//   y[:,p] = h2 @ W3[p] + b3[p]
// Memory-bound: ~640 MB of weights streamed once -> ~100 us floor @ 6.6 TB/s.
//
// Round 5: 128-thread blocks (2 waves/pixel) -> 16 waves/CU of TLP, per-lane
// tile 4x8 (acc=32 regs). Prefetch-distance-1 on the W1/W2 streams written as
// MACROS over named float4 vars (round 4's lambda+array version went to
// scratch: WRITE_SIZE 680 MB of spills). All array indices compile-time.
//
// lane mapping: g = tid>>4 (0..7) owns rows 4g..4g+3; kg = tid&15 owns cols
// {4kg..4kg+3} u {64+4kg..64+4kg+3}. Each W row = 2 dense 256B wave-pair loads.

constexpr int DIM_IN = 25;
constexpr int H      = 128;
constexpr int P      = 8000;
constexpr int BS     = 32;
constexpr float NEG  = 0.01f;

__device__ __forceinline__ float leaky(float v) { return v >= 0.f ? v : NEG * v; }

#define L1_LOAD(VL, VH, d) {                                                   \
    VL = *reinterpret_cast<const float4*>(W1p + (d) * H + c0);                 \
    VH = *reinterpret_cast<const float4*>(W1p + (d) * H + 64 + c0); }

#define L1_FMA(VL, VH, d) {                                                    \
    const float4 a4_ = *reinterpret_cast<const float4*>(&sxT[d][R0]);          \
    const float av_[4] = {a4_.x, a4_.y, a4_.z, a4_.w};                         \
    const float wv_[8] = {VL.x, VL.y, VL.z, VL.w, VH.x, VH.y, VH.z, VH.w};     \
    _Pragma("unroll")                                                          \
    for (int i_ = 0; i_ < 4; ++i_)                                             \
        _Pragma("unroll")                                                      \
        for (int c_ = 0; c_ < 8; ++c_)                                         \
            acc1[i_][c_] += av_[i_] * wv_[c_]; }

#define L2_LOAD(V0L, V0H, V1L, V1H, V2L, V2H, V3L, V3H, h0) {                  \
    V0L = *reinterpret_cast<const float4*>(W2p + ((h0) + 0) * H + c0);         \
    V0H = *reinterpret_cast<const float4*>(W2p + ((h0) + 0) * H + 64 + c0);    \
    V1L = *reinterpret_cast<const float4*>(W2p + ((h0) + 1) * H + c0);         \
    V1H = *reinterpret_cast<const float4*>(W2p + ((h0) + 1) * H + 64 + c0);    \
    V2L = *reinterpret_cast<const float4*>(W2p + ((h0) + 2) * H + c0);         \
    V2H = *reinterpret_cast<const float4*>(W2p + ((h0) + 2) * H + 64 + c0);    \
    V3L = *reinterpret_cast<const float4*>(W2p + ((h0) + 3) * H + c0);         \
    V3H = *reinterpret_cast<const float4*>(W2p + ((h0) + 3) * H + 64 + c0); }

#define L2_FMA(V0L, V0H, V1L, V1H, V2L, V2H, V3L, V3H, h0) {                   \
    const float wv_[4][8] = {                                                  \
        {V0L.x, V0L.y, V0L.z, V0L.w, V0H.x, V0H.y, V0H.z, V0H.w},             \
        {V1L.x, V1L.y, V1L.z, V1L.w, V1H.x, V1H.y, V1H.z, V1H.w},             \
        {V2L.x, V2L.y, V2L.z, V2L.w, V2H.x, V2H.y, V2H.z, V2H.w},             \
        {V3L.x, V3L.y, V3L.z, V3L.w, V3H.x, V3H.y, V3H.z, V3H.w}};            \
    _Pragma("unroll")                                                          \
    for (int i_ = 0; i_ < 4; ++i_) {                                           \
        const float4 a4_ =                                                     \
            *reinterpret_cast<const float4*>(&h1s[R0 + i_][(h0) ^ sw]);        \
        const float av_[4] = {a4_.x, a4_.y, a4_.z, a4_.w};                     \
        _Pragma("unroll")                                                      \
        for (int r_ = 0; r_ < 4; ++r_)                                         \
            _Pragma("unroll")                                                  \
            for (int c_ = 0; c_ < 8; ++c_)                                     \
                acc2[i_][c_] += av_[r_] * wv_[r_][c_];                         \
    } }

__global__ __launch_bounds__(128, 3) void pixel_mlp_kernel(
    const float* __restrict__ x,    // [BS][DIM_IN]
    const float* __restrict__ W1,   // [P][DIM_IN][H]
    const float* __restrict__ b1,   // [P][H]
    const float* __restrict__ W2,   // [P][H][H]
    const float* __restrict__ b2,   // [P][H]
    const float* __restrict__ W3,   // [P][H]
    const float* __restrict__ b3,   // [P]
    float* __restrict__ y)          // [BS][P]
{
    const int p  = blockIdx.x;
    const int t  = threadIdx.x;     // 0..127, two waves
    const int kg = t & 15;          // col group
    const int g  = t >> 4;          // row group 0..7 (bit 2 = wave id)
    const int c0 = kg << 2;         // first col of low half
    const int R0 = g << 2;          // first row (4 rows per lane)
    const int sw = g << 2;          // h1s bank swizzle (XOR on float index)

    __shared__ float sxT[DIM_IN][BS];   // x transposed: [d][b]
    __shared__ float h1s[BS][H];        // layer-1 activations, XOR-swizzled cols

    const float* W1p = W1 + (size_t)p * (DIM_IN * H);
    const float* W2p = W2 + (size_t)p * (H * H);

    // first W1 row in flight before x staging
    float4 wal, wah, wbl, wbh;
    L1_LOAD(wal, wah, 0)
    const float4 b1l = *reinterpret_cast<const float4*>(b1 + (size_t)p * H + c0);
    const float4 b1h = *reinterpret_cast<const float4*>(b1 + (size_t)p * H + 64 + c0);

    // stage x^T (800 elems, 128 threads)
    for (int i = t; i < DIM_IN * BS; i += 128) {
        const int d = i >> 5, b = i & 31;
        sxT[d][b] = x[b * DIM_IN + d];
    }
    __syncthreads();

    // ---------------- layer 1: h1 = leaky(x @ W1 + b1) ----------------
    float acc1[4][8];
    {
        const float bv[8] = {b1l.x, b1l.y, b1l.z, b1l.w, b1h.x, b1h.y, b1h.z, b1h.w};
        #pragma unroll
        for (int i = 0; i < 4; ++i)
            #pragma unroll
            for (int c = 0; c < 8; ++c)
                acc1[i][c] = bv[c];
    }

    #pragma unroll 1
    for (int d = 0; d < 24; d += 2) {      // d = 0,2,...,22
        L1_LOAD(wbl, wbh, d + 1)
        L1_FMA(wal, wah, d)
        L1_LOAD(wal, wah, d + 2)            // up to row 24
        L1_FMA(wbl, wbh, d + 1)
    }
    L1_FMA(wal, wah, 24)

    // small loads for later, issued early
    const float4 b2l = *reinterpret_cast<const float4*>(b2 + (size_t)p * H + c0);
    const float4 b2h = *reinterpret_cast<const float4*>(b2 + (size_t)p * H + 64 + c0);

    // W2 quad 0 in flight before the h1 LDS writes
    float4 q0l, q0h, q1l, q1h, q2l, q2h, q3l, q3h;
    float4 n0l, n0h, n1l, n1h, n2l, n2h, n3l, n3h;
    L2_LOAD(q0l, q0h, q1l, q1h, q2l, q2h, q3l, q3h, 0)

    // write h1 (leaky) with bank-group swizzle: float index ^= (g<<2)
    #pragma unroll
    for (int i = 0; i < 4; ++i) {
        float4 ol, oh;
        ol.x = leaky(acc1[i][0]); ol.y = leaky(acc1[i][1]);
        ol.z = leaky(acc1[i][2]); ol.w = leaky(acc1[i][3]);
        oh.x = leaky(acc1[i][4]); oh.y = leaky(acc1[i][5]);
        oh.z = leaky(acc1[i][6]); oh.w = leaky(acc1[i][7]);
        *reinterpret_cast<float4*>(&h1s[R0 + i][c0 ^ sw])        = ol;
        *reinterpret_cast<float4*>(&h1s[R0 + i][(64 + c0) ^ sw]) = oh;
    }
    __syncthreads();

    // ---------------- layer 2: h2 = leaky(h1 @ W2 + b2) ----------------
    float acc2[4][8];
    {
        const float bv[8] = {b2l.x, b2l.y, b2l.z, b2l.w, b2h.x, b2h.y, b2h.z, b2h.w};
        #pragma unroll
        for (int i = 0; i < 4; ++i)
            #pragma unroll
            for (int c = 0; c < 8; ++c)
                acc2[i][c] = bv[c];
    }

    #pragma unroll 1
    for (int h0 = 0; h0 < H - 8; h0 += 8) {   // h0 = 0,8,...,112
        L2_LOAD(n0l, n0h, n1l, n1h, n2l, n2h, n3l, n3h, h0 + 4)
        L2_FMA (q0l, q0h, q1l, q1h, q2l, q2h, q3l, q3h, h0)
        L2_LOAD(q0l, q0h, q1l, q1h, q2l, q2h, q3l, q3h, h0 + 8)
        L2_FMA (n0l, n0h, n1l, n1h, n2l, n2h, n3l, n3h, h0 + 4)
    }
    L2_LOAD(n0l, n0h, n1l, n1h, n2l, n2h, n3l, n3h, 124)
    L2_FMA (q0l, q0h, q1l, q1h, q2l, q2h, q3l, q3h, 120)
    L2_FMA (n0l, n0h, n1l, n1h, n2l, n2h, n3l, n3h, 124)

    // ---------------- layer 3: y = leaky(h2) @ W3 + b3 ----------------
    const float4 w3l = *reinterpret_cast<const float4*>(W3 + (size_t)p * H + c0);
    const float4 w3h = *reinterpret_cast<const float4*>(W3 + (size_t)p * H + 64 + c0);
    const float w3v[8] = {w3l.x, w3l.y, w3l.z, w3l.w, w3h.x, w3h.y, w3h.z, w3h.w};

    float part[4];
    #pragma unroll
    for (int i = 0; i < 4; ++i) {
        float s = 0.f;
        #pragma unroll
        for (int c = 0; c < 8; ++c)
            s += leaky(acc2[i][c]) * w3v[c];
        part[i] = s;
    }
    // reduce across the 16 kg lanes (xor masks 1,2,4,8 stay within the group)
    #pragma unroll
    for (int m = 8; m >= 1; m >>= 1) {
        #pragma unroll
        for (int i = 0; i < 4; ++i)
            part[i] += __shfl_xor(part[i], m);
    }
    if (kg == 0) {
        const float bias = b3[p];
        #pragma unroll
        for (int i = 0; i < 4; ++i)
            y[(size_t)(R0 + i) * P + p] = part[i] + bias;
    }
}

extern "C" void kernel_launch(void* const* d_in, const int* in_sizes, int n_in,
                              void* d_out, int out_size, void* d_ws, size_t ws_size,
                              hipStream_t stream) {
    const float* x  = (const float*)d_in[0];
    const float* W1 = (const float*)d_in[1];
    const float* b1 = (const float*)d_in[2];
    const float* W2 = (const float*)d_in[3];
    const float* b2 = (const float*)d_in[4];
    const float* W3 = (const float*)d_in[5];
    const float* b3 = (const float*)d_in[6];
    float* y = (float*)d_out;

    pixel_mlp_kernel<<<dim3(P), dim3(128), 0, stream>>>(x, W1, b1, W2, b2, W3, b3, y);
}

// Round 6
// 204.045 us; speedup vs baseline: 2.5609x; 2.5439x over previous
//
#include <hip/hip_runtime.h>

// PerceptronSP: 8000 independent per-pixel MLPs sharing input x.
//   h1 = leaky(x @ W1[p] + b1[p])   [32x25]@[25x128]
//   h2 = leaky(h1 @ W2[p] + b2[p])  [32x128]@[128x128]
//   y[:,p] = h2 @ W3[p] + b3[p]
// Memory-bound: ~640 MB of weights streamed once -> ~100 us floor @ 6.6 TB/s.
//
// Round 6: round-3 structure (one wave per pixel, 8x8 per-lane tile, NO
// explicit prefetch -- rounds 4/5 proved source-level double-buffering of
// this stream spills to scratch: WRITE_SIZE 569-680 MB). Lever instead:
// occupancy. h1 tile stored as packed bf16 pairs -> LDS 19.5 KB -> 11.4 KB
// -> 8 -> ~12-14 single-wave blocks/CU. Latency-bound BW scales with waves.
//
// lane = bg*16+kg: rows 8bg..8bg+7  x  cols {4kg..4kg+3} u {64+4kg..+3}.
// Each W1/W2 row = 2 dense 256B wave loads (1x request traffic).

constexpr int DIM_IN = 25;
constexpr int H      = 128;
constexpr int P      = 8000;
constexpr int BS     = 32;
constexpr float NEG  = 0.01f;

__device__ __forceinline__ float leaky(float v) { return v >= 0.f ? v : NEG * v; }

// pack two f32 into bf16x2 (round-to-nearest-even)
__device__ __forceinline__ unsigned pkbf2(float a, float b) {
    unsigned ua = __builtin_bit_cast(unsigned, a);
    unsigned ub = __builtin_bit_cast(unsigned, b);
    ua = (ua + 0x7fffu + ((ua >> 16) & 1u)) >> 16;
    ub = (ub + 0x7fffu + ((ub >> 16) & 1u)) >> 16;
    return ua | (ub << 16);
}
__device__ __forceinline__ float lo16(unsigned u) { return __builtin_bit_cast(float, u << 16); }
__device__ __forceinline__ float hi16(unsigned u) { return __builtin_bit_cast(float, u & 0xffff0000u); }

__global__ __launch_bounds__(64, 3) void pixel_mlp_kernel(
    const float* __restrict__ x,    // [BS][DIM_IN]
    const float* __restrict__ W1,   // [P][DIM_IN][H]
    const float* __restrict__ b1,   // [P][H]
    const float* __restrict__ W2,   // [P][H][H]
    const float* __restrict__ b2,   // [P][H]
    const float* __restrict__ W3,   // [P][H]
    const float* __restrict__ b3,   // [P]
    float* __restrict__ y)          // [BS][P]
{
    const int p   = blockIdx.x;
    const int t   = threadIdx.x;    // 0..63, one wave
    const int kg  = t & 15;         // col group
    const int bg  = t >> 4;         // row group: rows 8bg..8bg+7
    const int c0  = kg << 2;        // first col of low half
    const int r0  = bg << 3;        // first row
    const int sw2 = bg << 1;        // XOR swizzle on bf16-pair index (keeps b64 align)

    __shared__ float    sxT[DIM_IN][BS];  // x transposed: [d][b]   (3.2 KB)
    __shared__ unsigned h1u[BS][H / 2];   // h1 as bf16 pairs       (8 KB)

    const float* W1p = W1 + (size_t)p * (DIM_IN * H);
    const float* W2p = W2 + (size_t)p * (H * H);

    // stage x^T (800 elems, 64 threads)
    for (int i = t; i < DIM_IN * BS; i += 64) {
        const int d = i >> 5, b = i & 31;
        sxT[d][b] = x[b * DIM_IN + d];
    }
    __syncthreads();

    // ---------------- layer 1: h1 = leaky(x @ W1 + b1) ----------------
    float acc1[8][8];
    {
        const float4 bl = *reinterpret_cast<const float4*>(b1 + (size_t)p * H + c0);
        const float4 bh = *reinterpret_cast<const float4*>(b1 + (size_t)p * H + 64 + c0);
        const float bv[8] = {bl.x, bl.y, bl.z, bl.w, bh.x, bh.y, bh.z, bh.w};
        #pragma unroll
        for (int i = 0; i < 8; ++i)
            #pragma unroll
            for (int c = 0; c < 8; ++c)
                acc1[i][c] = bv[c];
    }

    for (int d = 0; d < DIM_IN; ++d) {
        const float4 a0 = *reinterpret_cast<const float4*>(&sxT[d][r0]);
        const float4 a1 = *reinterpret_cast<const float4*>(&sxT[d][r0 + 4]);
        const float av[8] = {a0.x, a0.y, a0.z, a0.w, a1.x, a1.y, a1.z, a1.w};
        const float4 wl = *reinterpret_cast<const float4*>(W1p + d * H + c0);
        const float4 wh = *reinterpret_cast<const float4*>(W1p + d * H + 64 + c0);
        const float wv[8] = {wl.x, wl.y, wl.z, wl.w, wh.x, wh.y, wh.z, wh.w};
        #pragma unroll
        for (int i = 0; i < 8; ++i)
            #pragma unroll
            for (int c = 0; c < 8; ++c)
                acc1[i][c] += av[i] * wv[c];
    }

    // write h1 (leaky) as bf16 pairs, pair-index XOR-swizzled by row stripe
    #pragma unroll
    for (int i = 0; i < 8; ++i) {
        uint2 lo, hi;
        lo.x = pkbf2(leaky(acc1[i][0]), leaky(acc1[i][1]));
        lo.y = pkbf2(leaky(acc1[i][2]), leaky(acc1[i][3]));
        hi.x = pkbf2(leaky(acc1[i][4]), leaky(acc1[i][5]));
        hi.y = pkbf2(leaky(acc1[i][6]), leaky(acc1[i][7]));
        *reinterpret_cast<uint2*>(&h1u[r0 + i][( 2 * kg      ) ^ sw2]) = lo;
        *reinterpret_cast<uint2*>(&h1u[r0 + i][(32 + 2 * kg  ) ^ sw2]) = hi;
    }
    __syncthreads();

    // ---------------- layer 2: h2 = leaky(h1 @ W2 + b2) ----------------
    float acc2[8][8];
    {
        const float4 bl = *reinterpret_cast<const float4*>(b2 + (size_t)p * H + c0);
        const float4 bh = *reinterpret_cast<const float4*>(b2 + (size_t)p * H + 64 + c0);
        const float bv[8] = {bl.x, bl.y, bl.z, bl.w, bh.x, bh.y, bh.z, bh.w};
        #pragma unroll
        for (int i = 0; i < 8; ++i)
            #pragma unroll
            for (int c = 0; c < 8; ++c)
                acc2[i][c] = bv[c];
    }

    #pragma unroll 2
    for (int h0 = 0; h0 < H; h0 += 4) {
        // W2 rows h0..h0+3: 8 dense 256B wave loads (the main HBM stream)
        float wv[4][8];
        #pragma unroll
        for (int r = 0; r < 4; ++r) {
            const float4 wl = *reinterpret_cast<const float4*>(W2p + (h0 + r) * H + c0);
            const float4 wh = *reinterpret_cast<const float4*>(W2p + (h0 + r) * H + 64 + c0);
            wv[r][0] = wl.x; wv[r][1] = wl.y; wv[r][2] = wl.z; wv[r][3] = wl.w;
            wv[r][4] = wh.x; wv[r][5] = wh.y; wv[r][6] = wh.z; wv[r][7] = wh.w;
        }
        // h1 rows r0..r0+7, cols h0..h0+3: one b64 read + 4 unpacks per row
        #pragma unroll
        for (int i = 0; i < 8; ++i) {
            const uint2 u = *reinterpret_cast<const uint2*>(&h1u[r0 + i][(h0 >> 1) ^ sw2]);
            const float av[4] = {lo16(u.x), hi16(u.x), lo16(u.y), hi16(u.y)};
            #pragma unroll
            for (int r = 0; r < 4; ++r)
                #pragma unroll
                for (int c = 0; c < 8; ++c)
                    acc2[i][c] += av[r] * wv[r][c];
        }
    }

    // ---------------- layer 3: y = leaky(h2) @ W3 + b3 ----------------
    const float4 w3l = *reinterpret_cast<const float4*>(W3 + (size_t)p * H + c0);
    const float4 w3h = *reinterpret_cast<const float4*>(W3 + (size_t)p * H + 64 + c0);
    const float w3v[8] = {w3l.x, w3l.y, w3l.z, w3l.w, w3h.x, w3h.y, w3h.z, w3h.w};

    float part[8];
    #pragma unroll
    for (int i = 0; i < 8; ++i) {
        float s = 0.f;
        #pragma unroll
        for (int c = 0; c < 8; ++c)
            s += leaky(acc2[i][c]) * w3v[c];
        part[i] = s;
    }
    // reduce across the 16 kg lanes (xor masks 1,2,4,8 stay within the group)
    #pragma unroll
    for (int m = 8; m >= 1; m >>= 1) {
        #pragma unroll
        for (int i = 0; i < 8; ++i)
            part[i] += __shfl_xor(part[i], m);
    }
    if (kg == 0) {
        const float bias = b3[p];
        #pragma unroll
        for (int i = 0; i < 8; ++i)
            y[(size_t)(r0 + i) * P + p] = part[i] + bias;
    }
}

extern "C" void kernel_launch(void* const* d_in, const int* in_sizes, int n_in,
                              void* d_out, int out_size, void* d_ws, size_t ws_size,
                              hipStream_t stream) {
    const float* x  = (const float*)d_in[0];
    const float* W1 = (const float*)d_in[1];
    const float* b1 = (const float*)d_in[2];
    const float* W2 = (const float*)d_in[3];
    const float* b2 = (const float*)d_in[4];
    const float* W3 = (const float*)d_in[5];
    const float* b3 = (const float*)d_in[6];
    float* y = (float*)d_out;

    pixel_mlp_kernel<<<dim3(P), dim3(64), 0, stream>>>(x, W1, b1, W2, b2, W3, b3, y);
}